// Round 4
// baseline (273.185 us; speedup 1.0000x reference)
//
#include <hip/hip_runtime.h>
#include <hip/hip_bf16.h>

// 15x15 VALID conv (cross-correlation) of 4096x4096 f32 -> 4082x4082 f32, + bias.
//
// Block: 256 threads = 4 waves. Output tile 256(x) x 32(y).
// Thread: tx = tid&63 (x), ty = tid>>6 (wave id, y). Computes 4 cols x 8 rows.
// LDS input tile: 46 rows x 272 floats = 49 KB -> 3 blocks/CU.
// R3 change: ky chunking 5x3 -> 3x5 (KCH=5). Row visits/thread 50 -> 36
// (-28% ds_read_b128) because rocprof showed the kernel is LDS-read-pipe
// bound (SQ_LDS_BANK_CONFLICT ~40% of cycles, VALUBusy only 45%).

#define IN_DIM   4096
#define OUT_DIM  4082   // 4096 - 15 + 1
#define KDIM     15
#define BTX      256    // block output tile x
#define BTY      32     // block output tile y
#define TIN_Y    46     // BTY + 14
#define TIN_XP   272    // BTX + 14 = 270, padded to 272 (16B multiple)
#define KCH      5      // ky rows per chunk
#define NCH      3      // number of chunks

__global__ __launch_bounds__(256) void conv15_kernel(
    const float* __restrict__ X, const float* __restrict__ Wt,
    const float* __restrict__ bias, float* __restrict__ out) {
  __shared__ float sX[TIN_Y * TIN_XP];

  const int tid = threadIdx.x;
  const int gx0 = blockIdx.x * BTX;   // first output col of block
  const int gy0 = blockIdx.y * BTY;   // first output row of block

  // ---- stage input tile (rows gy0..gy0+45, cols gx0..gx0+271) ----
  for (int idx = tid; idx < TIN_Y * (TIN_XP / 4); idx += 256) {
    const int r  = idx / (TIN_XP / 4);
    const int c4 = (idx - r * (TIN_XP / 4)) * 4;
    const int gr = gy0 + r;
    const int gc = gx0 + c4;
    float4 v = make_float4(0.f, 0.f, 0.f, 0.f);
    if (gr < IN_DIM) {
      const float* row = X + (size_t)gr * IN_DIM;
      if (gc + 3 < IN_DIM) {
        v = *reinterpret_cast<const float4*>(row + gc);
      } else {
        if (gc + 0 < IN_DIM) v.x = row[gc + 0];
        if (gc + 1 < IN_DIM) v.y = row[gc + 1];
        if (gc + 2 < IN_DIM) v.z = row[gc + 2];
        if (gc + 3 < IN_DIM) v.w = row[gc + 3];
      }
    }
    *reinterpret_cast<float4*>(sX + r * TIN_XP + c4) = v;
  }
  __syncthreads();

  // ---- compute ----
  const int tx = tid & 63;       // 0..63, wave lanes contiguous in x
  const int ty = tid >> 6;       // 0..3  (wave id)
  const int lcol  = tx * 4;      // local col of first output (16B aligned)
  const int lrow0 = ty * 8;      // local row of first output

  float acc[8][4];
#pragma unroll
  for (int i = 0; i < 8; ++i)
#pragma unroll
    for (int j = 0; j < 4; ++j) acc[i][j] = 0.f;

#pragma unroll 1
  for (int c = 0; c < NCH; ++c) {
    // weights for ky in [KCH*c, KCH*c+KCH) -- uniform loads (scalar cache)
    float w[KCH][KDIM];
#pragma unroll
    for (int kyl = 0; kyl < KCH; ++kyl)
#pragma unroll
      for (int kx = 0; kx < KDIM; ++kx)
        w[kyl][kx] = Wt[(c * KCH + kyl) * KDIM + kx];

    // input rows needed this chunk: lrow0 + KCH*c + ir, ir in [0, 8+KCH-1)
#pragma unroll
    for (int ir = 0; ir < 8 + KCH - 1; ++ir) {
      float buf[20];
      const float* p = sX + (lrow0 + c * KCH + ir) * TIN_XP + lcol;
#pragma unroll
      for (int k = 0; k < 5; ++k) {
        const float4 v = *reinterpret_cast<const float4*>(p + k * 4);
        buf[k * 4 + 0] = v.x; buf[k * 4 + 1] = v.y;
        buf[k * 4 + 2] = v.z; buf[k * 4 + 3] = v.w;
      }
#pragma unroll
      for (int dy = 0; dy < 8; ++dy) {
        const int kyl = ir - dy;            // compile-time after unroll
        if (kyl >= 0 && kyl < KCH) {
#pragma unroll
          for (int kx = 0; kx < KDIM; ++kx)
#pragma unroll
            for (int j = 0; j < 4; ++j)
              acc[dy][j] = fmaf(buf[kx + j], w[kyl][kx], acc[dy][j]);
        }
      }
    }
  }

  // ---- store (float2: OUT_DIM even, ox even -> pairs never straddle) ----
  const float b = bias[0];
#pragma unroll
  for (int dy = 0; dy < 8; ++dy) {
    const int oy = gy0 + lrow0 + dy;
    if (oy < OUT_DIM) {
      const int ox = gx0 + lcol;
      float* orow = out + (size_t)oy * OUT_DIM;
#pragma unroll
      for (int j2 = 0; j2 < 2; ++j2) {
        if (ox + j2 * 2 + 1 < OUT_DIM) {
          float2 v2 = make_float2(acc[dy][j2 * 2 + 0] + b,
                                  acc[dy][j2 * 2 + 1] + b);
          *reinterpret_cast<float2*>(orow + ox + j2 * 2) = v2;
        }
      }
    }
  }
}

extern "C" void kernel_launch(void* const* d_in, const int* in_sizes, int n_in,
                              void* d_out, int out_size, void* d_ws, size_t ws_size,
                              hipStream_t stream) {
  const float* X    = (const float*)d_in[0];
  const float* Wt   = (const float*)d_in[1];
  const float* bias = (const float*)d_in[2];
  float* out = (float*)d_out;

  dim3 grid((OUT_DIM + BTX - 1) / BTX,    // 16
            (OUT_DIM + BTY - 1) / BTY);   // 128
  conv15_kernel<<<grid, 256, 0, stream>>>(X, Wt, bias, out);
}

// Round 5
// 146.547 us; speedup vs baseline: 1.8641x; 1.8641x over previous
//
#include <hip/hip_runtime.h>
#include <hip/hip_bf16.h>

// 15x15 VALID conv as banded-Toeplitz MFMA (bf16 in, fp32 accum).
// For each ky: O_tile[16x16] += A(16x32 image patch) x B_ky(32x16 Toeplitz),
// where B_ky[k][n] = w[ky][k-n] if 0<=k-n<=14 else 0.  K=32 exactly covers
// n(<=15) + kx(<=14). 15 MFMAs per output tile total.
//
// Block: 256 thr (4 waves), output 128(y) x 112(x). Input slab 142x128 bf16
// in LDS, XOR-swizzled (byte ^= (row&7)<<4) to kill the stride-256B 32-way
// bank conflict on A-reads. Toeplitz B: 15x16x32 bf16 in LDS, built once.
// LDS = 36352 + 15360 = 51712 B -> 3 blocks/CU.

#define IN_DIM   4096
#define OUT_DIM  4082
#define KDIM     15
#define BM       128           // output rows per block
#define BN       112           // output cols per block
#define SLAB_R   142           // BM + 14
#define SLAB_C   128           // BN + 16 (K=32 window reach from xt=96)
#define NTX      7             // 16-col tiles per block

typedef __attribute__((ext_vector_type(8))) short  short8;
typedef __attribute__((ext_vector_type(4))) float  f32x4;

__global__ __launch_bounds__(256) void conv15_mfma(
    const float* __restrict__ X, const float* __restrict__ Wt,
    const float* __restrict__ bias, float* __restrict__ out) {
  __shared__ __align__(16) unsigned short sX[SLAB_R * SLAB_C];  // 36352 B
  __shared__ __align__(16) unsigned short sB[KDIM * 16 * 32];   // 15360 B

  const int tid = threadIdx.x;
  const int x0 = blockIdx.x * BN;
  const int y0 = blockIdx.y * BM;

  // ---- build Toeplitz B: sB[ky][n][k] = w[ky][k-n] in band, else 0 ----
  for (int idx = tid; idx < KDIM * 512; idx += 256) {
    const int ky = idx >> 9;
    const int n  = (idx >> 5) & 15;
    const int k  = idx & 31;
    const int kx = k - n;
    unsigned short v = 0;
    if (kx >= 0 && kx < KDIM) {
      __hip_bfloat16 h = __float2bfloat16(Wt[ky * KDIM + kx]);
      v = *reinterpret_cast<const unsigned short*>(&h);
    }
    sB[idx] = v;
  }

  // ---- stage input slab (f32 -> bf16), swizzled writes ----
  // 142 rows x 16 chunks of 8 elems = 2272 chunks
  for (int idx = tid; idx < SLAB_R * (SLAB_C / 8); idx += 256) {
    const int r  = idx >> 4;
    const int c8 = (idx & 15) << 3;
    const int gr = y0 + r;
    const int gc = x0 + c8;
    float f[8];
    if (gr < IN_DIM && gc + 7 < IN_DIM) {
      const float* p = X + (size_t)gr * IN_DIM + gc;
      const f32x4 a = *reinterpret_cast<const f32x4*>(p);
      const f32x4 b = *reinterpret_cast<const f32x4*>(p + 4);
      f[0] = a.x; f[1] = a.y; f[2] = a.z; f[3] = a.w;
      f[4] = b.x; f[5] = b.y; f[6] = b.z; f[7] = b.w;
    } else {
#pragma unroll
      for (int j = 0; j < 8; ++j)
        f[j] = (gr < IN_DIM && gc + j < IN_DIM)
                 ? X[(size_t)gr * IN_DIM + gc + j] : 0.f;
    }
    short8 pk;
#pragma unroll
    for (int j = 0; j < 8; ++j) {
      __hip_bfloat16 h = __float2bfloat16(f[j]);
      pk[j] = *reinterpret_cast<const short*>(&h);
    }
    const int byte = (r * (SLAB_C * 2) + c8 * 2) ^ ((r & 7) << 4);
    *reinterpret_cast<short8*>(reinterpret_cast<char*>(sX) + byte) = pk;
  }
  __syncthreads();

  // ---- compute: wave w owns tile-rows {2w, 2w+1} x 7 tile-cols ----
  const int lane = tid & 63;
  const int wv   = tid >> 6;
  const int m    = lane & 15;   // A row within tile / D col
  const int g    = lane >> 4;   // k-chunk / D row-quad

  f32x4 acc[2][NTX];
#pragma unroll
  for (int a = 0; a < 2; ++a)
#pragma unroll
    for (int b = 0; b < NTX; ++b)
      acc[a][b] = (f32x4){0.f, 0.f, 0.f, 0.f};

#pragma unroll 1
  for (int ky = 0; ky < KDIM; ++ky) {
    const short8 bfrag = *reinterpret_cast<const short8*>(
        reinterpret_cast<const char*>(sB) + ky * 1024 + m * 64 + g * 16);
#pragma unroll
    for (int ty = 0; ty < 2; ++ty) {
      const int r = (2 * wv + ty) * 16 + m + ky;     // slab row of A
      const int rowbyte = r * (SLAB_C * 2);
      const int sw = (r & 7) << 4;
#pragma unroll
      for (int xt = 0; xt < NTX; ++xt) {
        const int byte = (rowbyte + (xt * 16 + g * 8) * 2) ^ sw;
        const short8 afrag = *reinterpret_cast<const short8*>(
            reinterpret_cast<const char*>(sX) + byte);
        acc[ty][xt] = __builtin_amdgcn_mfma_f32_16x16x32_bf16(
            afrag, bfrag, acc[ty][xt], 0, 0, 0);
      }
    }
  }

  // ---- store: D col = lane&15, row = (lane>>4)*4 + reg  [m89/m91] ----
  const float bv = bias[0];
#pragma unroll
  for (int ty = 0; ty < 2; ++ty) {
    const int gy0 = y0 + (2 * wv + ty) * 16 + g * 4;
#pragma unroll
    for (int xt = 0; xt < NTX; ++xt) {
      const int ox = x0 + xt * 16 + m;
      if (ox < OUT_DIM) {
#pragma unroll
        for (int q = 0; q < 4; ++q) {
          const int oy = gy0 + q;
          if (oy < OUT_DIM)
            out[(size_t)oy * OUT_DIM + ox] = acc[ty][xt][q] + bv;
        }
      }
    }
  }
}

extern "C" void kernel_launch(void* const* d_in, const int* in_sizes, int n_in,
                              void* d_out, int out_size, void* d_ws, size_t ws_size,
                              hipStream_t stream) {
  const float* X    = (const float*)d_in[0];
  const float* Wt   = (const float*)d_in[1];
  const float* bias = (const float*)d_in[2];
  float* out = (float*)d_out;

  dim3 grid((OUT_DIM + BN - 1) / BN,    // 37
            (OUT_DIM + BM - 1) / BM);   // 32
  conv15_mfma<<<grid, 256, 0, stream>>>(X, Wt, bias, out);
}

// Round 7
// 142.089 us; speedup vs baseline: 1.9226x; 1.0314x over previous
//
#include <hip/hip_runtime.h>
#include <hip/hip_bf16.h>

// 15x15 VALID conv as banded-Toeplitz MFMA (bf16 in, fp32 accum).
// Per ky: O_tile[16x16] += A(16x32 image patch) x B_ky(32x16 Toeplitz),
// B_ky[k][n] = w[ky][k-n] for 0<=k-n<=14 else 0. 15 MFMAs per output tile.
//
// R6 (from rocprof R5: latency-bound, MfmaUtil 9.4%, VALU = XOR addr math,
// sB reads 8-way conflicted):
//  - padded slab stride 240 B instead of XOR swizzle: bank shift 28/row ->
//    only (m,m+8) 2-way alias (free, m136); A-read addr = base + imm offset.
//  - B-frags hoisted to 60 VGPRs (no per-MFMA sB reads).
//  - full ky unroll, __launch_bounds__(256,3) to keep 3 blocks/CU.
// Block: 256 thr, output 128(y) x 96(x). LDS: slab 142x240B + sB 15360B = 49.4 KB.

#define IN_DIM   4096
#define OUT_DIM  4082
#define KDIM     15
#define BM       128
#define BN       96
#define NTX      6             // 16-col output tiles per block
#define SLAB_R   142           // BM + 14
#define SLAB_CE  120           // bf16 elems per slab row (cols used: 0..111)
#define SLAB_CB  240           // bytes per slab row
#define SLAB_CH  15            // 16-B chunks per row

typedef __attribute__((ext_vector_type(8))) short  short8;
typedef __attribute__((ext_vector_type(4))) float  f32x4;

__global__ __launch_bounds__(256, 3) void conv15_mfma(
    const float* __restrict__ X, const float* __restrict__ Wt,
    const float* __restrict__ bias, float* __restrict__ out) {
  __shared__ __align__(16) unsigned short sX[SLAB_R * SLAB_CE];  // 34080 B
  __shared__ __align__(16) unsigned short sB[KDIM * 16 * 32];    // 15360 B

  const int tid = threadIdx.x;
  const int x0 = blockIdx.x * BN;
  const int y0 = blockIdx.y * BM;

  // ---- build Toeplitz B: sB[ky][n][k] = w[ky][k-n] in band, else 0 ----
  for (int idx = tid; idx < KDIM * 512; idx += 256) {
    const int ky = idx >> 9;
    const int n  = (idx >> 5) & 15;
    const int k  = idx & 31;
    const int kx = k - n;
    unsigned short v = 0;
    if (kx >= 0 && kx < KDIM) {
      __hip_bfloat16 h = __float2bfloat16(Wt[ky * KDIM + kx]);
      v = *reinterpret_cast<const unsigned short*>(&h);
    }
    sB[idx] = v;
  }

  // ---- stage input slab (f32 -> bf16), linear padded-stride writes ----
  // 142 rows x 15 chunks of 8 elems = 2130 chunks
  for (int idx = tid; idx < SLAB_R * SLAB_CH; idx += 256) {
    const int r = idx / SLAB_CH;
    const int c = idx - r * SLAB_CH;
    int gr = y0 + r;           if (gr > IN_DIM - 1) gr = IN_DIM - 1;
    int gc = x0 + c * 8;       if (gc > IN_DIM - 8) gc = IN_DIM - 8;
    // clamped rows/cols only ever feed outputs with oy/ox >= 4082 (unstored)
    const float* p = X + (size_t)gr * IN_DIM + gc;
    const f32x4 a = *reinterpret_cast<const f32x4*>(p);
    const f32x4 b = *reinterpret_cast<const f32x4*>(p + 4);
    float f[8] = {a.x, a.y, a.z, a.w, b.x, b.y, b.z, b.w};
    short8 pk;
#pragma unroll
    for (int j = 0; j < 8; ++j) {
      __hip_bfloat16 h = __float2bfloat16(f[j]);
      pk[j] = *reinterpret_cast<const short*>(&h);
    }
    *reinterpret_cast<short8*>(
        reinterpret_cast<char*>(sX) + r * SLAB_CB + c * 16) = pk;
  }
  __syncthreads();

  // ---- compute: wave wv owns tile-rows {2wv, 2wv+1} x 6 tile-cols ----
  const int lane = tid & 63;
  const int wv   = tid >> 6;
  const int m    = lane & 15;   // A row within tile / D col
  const int g    = lane >> 4;   // k-chunk / D row-quad

  // B fragments -> registers (static indexing after unroll)
  short8 bf[KDIM];
#pragma unroll
  for (int ky = 0; ky < KDIM; ++ky)
    bf[ky] = *reinterpret_cast<const short8*>(
        reinterpret_cast<const char*>(sB) + ky * 1024 + m * 64 + g * 16);

  f32x4 acc[2][NTX];
#pragma unroll
  for (int a = 0; a < 2; ++a)
#pragma unroll
    for (int b = 0; b < NTX; ++b)
      acc[a][b] = (f32x4){0.f, 0.f, 0.f, 0.f};

  // base addr per ty; all reads then use compile-time immediates
  const char* base0 = reinterpret_cast<const char*>(sX)
                    + (32 * wv + m) * SLAB_CB + 16 * g;
  const char* base1 = base0 + 16 * SLAB_CB;

#pragma unroll
  for (int ky = 0; ky < KDIM; ++ky) {
#pragma unroll
    for (int xt = 0; xt < NTX; ++xt) {
      const short8 a0 = *reinterpret_cast<const short8*>(
          base0 + ky * SLAB_CB + 32 * xt);
      acc[0][xt] = __builtin_amdgcn_mfma_f32_16x16x32_bf16(
          a0, bf[ky], acc[0][xt], 0, 0, 0);
    }
#pragma unroll
    for (int xt = 0; xt < NTX; ++xt) {
      const short8 a1 = *reinterpret_cast<const short8*>(
          base1 + ky * SLAB_CB + 32 * xt);
      acc[1][xt] = __builtin_amdgcn_mfma_f32_16x16x32_bf16(
          a1, bf[ky], acc[1][xt], 0, 0, 0);
    }
  }

  // ---- store: D col = lane&15, row = (lane>>4)*4 + reg  [m89/m91] ----
  const float bv = bias[0];
#pragma unroll
  for (int ty = 0; ty < 2; ++ty) {
    const int gy0 = y0 + (2 * wv + ty) * 16 + g * 4;
#pragma unroll
    for (int xt = 0; xt < NTX; ++xt) {
      const int ox = x0 + xt * 16 + m;
      if (ox < OUT_DIM) {
#pragma unroll
        for (int q = 0; q < 4; ++q) {
          const int oy = gy0 + q;
          if (oy < OUT_DIM)
            out[(size_t)oy * OUT_DIM + ox] = acc[ty][xt][q] + bv;
        }
      }
    }
  }
}

extern "C" void kernel_launch(void* const* d_in, const int* in_sizes, int n_in,
                              void* d_out, int out_size, void* d_ws, size_t ws_size,
                              hipStream_t stream) {
  const float* X    = (const float*)d_in[0];
  const float* Wt   = (const float*)d_in[1];
  const float* bias = (const float*)d_in[2];
  float* out = (float*)d_out;

  dim3 grid((OUT_DIM + BN - 1) / BN,    // 43
            (OUT_DIM + BM - 1) / BM);   // 32
  conv15_mfma<<<grid, 256, 0, stream>>>(X, Wt, bias, out);
}

// Round 8
// 129.772 us; speedup vs baseline: 2.1051x; 1.0949x over previous
//
#include <hip/hip_runtime.h>
#include <hip/hip_bf16.h>

// 15x15 VALID conv as banded-Toeplitz MFMA (bf16 in, fp32 accum).
// Per ky: O_tile[16x16] += A(16x32 image patch) x B_ky(32x16 Toeplitz),
// B_ky[k][n] = w[ky][k-n] for 0<=k-n<=14 else 0. 15 MFMAs per output tile.
//
// R8 (from rocprof R7: latency-bound — MfmaUtil 10%, VALU 14%, occ 23.5%,
// conflicts unchanged vs R5 so they were never the A-reads):
//  - sB table (15.4 KB) -> 450 B bf16 weight table; per-thread one-time
//    B-frag build into 60 VGPRs (compiler can no longer leave them in LDS).
//  - BN 96->80 (NTX=5), slab stride 192 B (uniform banks, linear staging),
//    LDS 27.7 KB total + __launch_bounds__(256,4) -> 4 blocks/CU (16 waves).
//  - bijective XCD swizzle: 1664 blocks = 8 x 208, 4 grid-rows per XCD.
//  - bias folded into accumulator init.

#define IN_DIM   4096
#define OUT_DIM  4082
#define KDIM     15
#define BM       128
#define BN       80
#define NTX      5             // 16-col output tiles per block
#define SLAB_R   142           // BM + 14
#define SLAB_CE  96            // bf16 elems per slab row (cols used: 0..95)
#define SLAB_CB  192           // bytes per slab row
#define SLAB_CH  12            // 16-B chunks per row
#define GRID_X   52            // ceil(4082/80)
#define GRID_Y   32            // ceil(4082/128)
#define NWG      (GRID_X * GRID_Y)   // 1664 = 8 * 208
#define CPX      (NWG / 8)           // 208 blocks per XCD

typedef __attribute__((ext_vector_type(8))) short  short8;
typedef __attribute__((ext_vector_type(4))) float  f32x4;

__global__ __launch_bounds__(256, 4) void conv15_mfma(
    const float* __restrict__ X, const float* __restrict__ Wt,
    const float* __restrict__ bias, float* __restrict__ out) {
  __shared__ __align__(16) unsigned short sX[SLAB_R * SLAB_CE];  // 27648 B
  __shared__ __align__(16) unsigned short sW[KDIM * KDIM];       // 450 B

  const int tid = threadIdx.x;

  // ---- XCD-aware bijective swizzle (1664 = 8 XCDs x 208) ----
  const int bid = blockIdx.x;
  const int lin = (bid & 7) * CPX + (bid >> 3);
  const int bx  = lin % GRID_X;
  const int by  = lin / GRID_X;
  const int x0 = bx * BN;
  const int y0 = by * BM;

  // ---- compact bf16 weight table ----
  if (tid < KDIM * KDIM) {
    __hip_bfloat16 h = __float2bfloat16(Wt[tid]);
    sW[tid] = *reinterpret_cast<const unsigned short*>(&h);
  }

  // ---- stage input slab (f32 -> bf16), linear writes (byte = 16*idx) ----
  for (int idx = tid; idx < SLAB_R * SLAB_CH; idx += 256) {
    const int r = idx / SLAB_CH;
    const int c = idx - r * SLAB_CH;
    int gr = y0 + r;           if (gr > IN_DIM - 1) gr = IN_DIM - 1;
    int gc = x0 + c * 8;       if (gc > IN_DIM - 8) gc = IN_DIM - 8;
    // clamped rows/cols only ever feed band-zero or unstored outputs
    const float* p = X + (size_t)gr * IN_DIM + gc;
    const f32x4 a = *reinterpret_cast<const f32x4*>(p);
    const f32x4 b = *reinterpret_cast<const f32x4*>(p + 4);
    float f[8] = {a.x, a.y, a.z, a.w, b.x, b.y, b.z, b.w};
    short8 pk;
#pragma unroll
    for (int j = 0; j < 8; ++j) {
      __hip_bfloat16 h = __float2bfloat16(f[j]);
      pk[j] = *reinterpret_cast<const short*>(&h);
    }
    *reinterpret_cast<short8*>(
        reinterpret_cast<char*>(sX) + r * SLAB_CB + c * 16) = pk;
  }
  __syncthreads();

  const int lane = tid & 63;
  const int wv   = tid >> 6;
  const int m    = lane & 15;   // A row within tile / D col
  const int g    = lane >> 4;   // k-chunk / D row-quad

  // ---- build B fragments in registers: bf[ky][j] = w[ky][g*8+j-m] ----
  short8 bf[KDIM];
#pragma unroll
  for (int ky = 0; ky < KDIM; ++ky) {
    short8 t;
#pragma unroll
    for (int j = 0; j < 8; ++j) {
      const int kx = g * 8 + j - m;
      const int cl = kx < 0 ? 0 : (kx > 14 ? 14 : kx);
      const unsigned short v = sW[ky * KDIM + cl];
      t[j] = (kx >= 0 && kx <= 14) ? (short)v : (short)0;
    }
    bf[ky] = t;
  }

  // ---- accumulators (bias folded into init) ----
  const float bv = bias[0];
  f32x4 acc[2][NTX];
#pragma unroll
  for (int a = 0; a < 2; ++a)
#pragma unroll
    for (int b = 0; b < NTX; ++b)
      acc[a][b] = (f32x4){bv, bv, bv, bv};

  // base addr per ty; all reads use compile-time immediates
  const char* base0 = reinterpret_cast<const char*>(sX)
                    + (32 * wv + m) * SLAB_CB + 16 * g;
  const char* base1 = base0 + 16 * SLAB_CB;

#pragma unroll
  for (int ky = 0; ky < KDIM; ++ky) {
#pragma unroll
    for (int xt = 0; xt < NTX; ++xt) {
      const short8 a0 = *reinterpret_cast<const short8*>(
          base0 + ky * SLAB_CB + 32 * xt);
      acc[0][xt] = __builtin_amdgcn_mfma_f32_16x16x32_bf16(
          a0, bf[ky], acc[0][xt], 0, 0, 0);
    }
#pragma unroll
    for (int xt = 0; xt < NTX; ++xt) {
      const short8 a1 = *reinterpret_cast<const short8*>(
          base1 + ky * SLAB_CB + 32 * xt);
      acc[1][xt] = __builtin_amdgcn_mfma_f32_16x16x32_bf16(
          a1, bf[ky], acc[1][xt], 0, 0, 0);
    }
  }

  // ---- store: D col = lane&15, row = (lane>>4)*4 + reg  [m89/m91] ----
#pragma unroll
  for (int ty = 0; ty < 2; ++ty) {
    const int gy0 = y0 + (2 * wv + ty) * 16 + g * 4;
#pragma unroll
    for (int xt = 0; xt < NTX; ++xt) {
      const int ox = x0 + xt * 16 + m;
      if (ox < OUT_DIM) {
#pragma unroll
        for (int q = 0; q < 4; ++q) {
          const int oy = gy0 + q;
          if (oy < OUT_DIM)
            out[(size_t)oy * OUT_DIM + ox] = acc[ty][xt][q];
        }
      }
    }
  }
}

extern "C" void kernel_launch(void* const* d_in, const int* in_sizes, int n_in,
                              void* d_out, int out_size, void* d_ws, size_t ws_size,
                              hipStream_t stream) {
  const float* X    = (const float*)d_in[0];
  const float* Wt   = (const float*)d_in[1];
  const float* bias = (const float*)d_in[2];
  float* out = (float*)d_out;

  conv15_mfma<<<NWG, 256, 0, stream>>>(X, Wt, bias, out);
}